// Round 14
// baseline (66.557 us; speedup 1.0000x reference)
//
#include <hip/hip_runtime.h>
#include <hip/hip_bf16.h>
#include <math.h>

#define B_ 128
#define IN_ 1024
#define D_ 128
#define H_ 512
#define S_ 256

typedef __attribute__((ext_vector_type(8))) short short8v;
typedef __attribute__((ext_vector_type(8))) unsigned short ushort8v;
typedef __attribute__((ext_vector_type(4))) unsigned short ushort4v;
typedef __attribute__((ext_vector_type(4))) float f32x4;

__device__ __forceinline__ float softplusf(float x) {
  return fmaxf(x, 0.f) + log1pf(expf(-fabsf(x)));
}

__device__ __forceinline__ unsigned short f2bf(float f) {
  unsigned u = __float_as_uint(f);
  unsigned r = (u + 0x7fff + ((u >> 16) & 1)) >> 16;   // RNE
  return (unsigned short)r;
}

// ============ fused prep kernel (best-measured; unchanged) ============
__global__ __launch_bounds__(256) void Kprep(
    const float* __restrict__ x, const float* __restrict__ w,
    const float* __restrict__ z, const float* __restrict__ W,
    const float* __restrict__ cvec, const float* __restrict__ W1,
    const float* __restrict__ b1, const float* __restrict__ W2,
    unsigned short* __restrict__ Bp, float* __restrict__ l2part,
    float* __restrict__ pxw_part, float* __restrict__ zb1,
    float* __restrict__ fzw_part) {
  __shared__ float smem[1024];
  const int blk = blockIdx.x;
  const int t = threadIdx.x;

  if (blk < 64) {
    const int o = (blk * 256 + t) * 4;
    const int frag = o >> 9;
    const int l = (o >> 3) & 63;
    const int j0 = o & 7;
    const int h = (frag >> 2) * 16 + (l & 15);
    const int k0 = (frag & 3) * 32 + ((l >> 4) << 3) + j0;
    const float4 v = *(const float4*)(W1 + (size_t)h * 256 + 128 + k0);
    ushort4v u;
    u[0] = f2bf(v.x); u[1] = f2bf(v.y); u[2] = f2bf(v.z); u[3] = f2bf(v.w);
    *(ushort4v*)(Bp + o) = u;
  } else if (blk < 1088) {
    const int bb = blk - 64;
    const int b = bb >> 3, kc = bb & 7;
    float* xs = smem;            // 128
    float* p2 = smem + 128;      // 256
    if (t < 128) xs[t] = x[b * IN_ + kc * 128 + t];
    __syncthreads();
    const int d = t & 127, ks = t >> 7;
    const float* __restrict__ Wp = W + (size_t)(kc * 128 + ks * 64) * D_ + d;
    float s = 0.f;
    #pragma unroll 8
    for (int i = 0; i < 64; ++i) s = fmaf(xs[ks * 64 + i], Wp[(size_t)i * D_], s);
    p2[ks * 128 + d] = s;
    __syncthreads();
    if (t < 128) l2part[((size_t)b * 8 + kc) * 128 + t] = p2[t] + p2[128 + t];
  } else if (blk < 1600) {
    const int bb = blk - 1088;
    const int b = bb >> 2, ic = bb & 3;
    float* ws_ = smem;           // 128
    float* red = smem + 128;     // 4
    if (t < 128) ws_[t] = w[b * 128 + t];
    __syncthreads();
    const int chunk = t & 15, rgrp = t >> 4;
    float wreg[8];
    #pragma unroll
    for (int j = 0; j < 8; ++j) wreg[j] = ws_[chunk * 8 + j];
    float term = 0.f;
    #pragma unroll 2
    for (int it = 0; it < 16; ++it) {
      const int i = ic * 256 + it * 16 + rgrp;
      const float4* __restrict__ rp = (const float4*)(W + (size_t)i * D_ + chunk * 8);
      const float4 va = rp[0], vb = rp[1];
      float dot = 0.f;
      dot = fmaf(va.x, wreg[0], dot); dot = fmaf(va.y, wreg[1], dot);
      dot = fmaf(va.z, wreg[2], dot); dot = fmaf(va.w, wreg[3], dot);
      dot = fmaf(vb.x, wreg[4], dot); dot = fmaf(vb.y, wreg[5], dot);
      dot = fmaf(vb.z, wreg[6], dot); dot = fmaf(vb.w, wreg[7], dot);
      dot += __shfl_xor(dot, 1); dot += __shfl_xor(dot, 2);
      dot += __shfl_xor(dot, 4); dot += __shfl_xor(dot, 8);
      if (chunk == 0) {
        const float lg = dot + cvec[i];
        term += x[b * IN_ + i] * lg - softplusf(lg);
      }
    }
    #pragma unroll
    for (int o = 32; o > 0; o >>= 1) term += __shfl_down(term, o);
    const int lane = t & 63, wid = t >> 6;
    if (lane == 0) red[wid] = term;
    __syncthreads();
    if (t == 0) pxw_part[b * 4 + ic] = red[0] + red[1] + red[2] + red[3];
  } else {
    const int bb = blk - 1600;
    const int bq = bb >> 3, hc = bb & 7;
    float* zs  = smem;           // 512
    float* ws2 = smem + 512;     // 512
    for (int e = t; e < 512; e += 256) {
      zs[e]  = z[bq * 512 + e];
      ws2[e] = w[bq * 512 + e];
    }
    __syncthreads();
    const int bs = t >> 6, lane = t & 63;
    const int c16 = lane & 15, rsub = lane >> 4;
    const int b = bq * 4 + bs;
    float zreg[16];
    #pragma unroll
    for (int j = 0; j < 16; ++j)
      zreg[j] = (c16 < 8) ? zs[bs * 128 + c16 * 16 + j]
                          : ws2[bs * 128 + c16 * 16 - 128 + j];
    float fpacc = 0.f;
    #pragma unroll 2
    for (int it = 0; it < 16; ++it) {
      const int h = hc * 64 + it * 4 + rsub;
      const float4* __restrict__ rp = (const float4*)(W1 + (size_t)h * 256 + c16 * 16);
      float dot = 0.f;
      #pragma unroll
      for (int q = 0; q < 4; ++q) {
        const float4 v = rp[q];
        dot = fmaf(v.x, zreg[4 * q + 0], dot);
        dot = fmaf(v.y, zreg[4 * q + 1], dot);
        dot = fmaf(v.z, zreg[4 * q + 2], dot);
        dot = fmaf(v.w, zreg[4 * q + 3], dot);
      }
      dot += __shfl_xor(dot, 1); dot += __shfl_xor(dot, 2);
      dot += __shfl_xor(dot, 4);
      const float other = __shfl_xor(dot, 8);
      if (c16 == 0) {
        const float zp = dot + b1[h];
        zb1[(size_t)b * H_ + h] = zp;
        fpacc += fmaxf(zp + other, 0.f) * W2[h];
      }
    }
    fpacc += __shfl_xor(fpacc, 16);
    fpacc += __shfl_xor(fpacc, 32);
    if (lane == 0) fzw_part[b * 8 + hc] = fpacc;
  }
}

// ============ main fused kernel: one block per b (unchanged) ============
__global__ __launch_bounds__(1024) void Kmain(
    const float* __restrict__ wt, const unsigned short* __restrict__ Bp,
    const float* __restrict__ zb1, const float* __restrict__ W2,
    const float* __restrict__ b2, const float* __restrict__ l2part,
    const float* __restrict__ bvec, const float* __restrict__ w,
    const float* __restrict__ pxw_part, const float* __restrict__ fzw_part,
    float* __restrict__ out) {
  const int b = blockIdx.x;
  const int t = threadIdx.x;
  const int lane = t & 63, wvid = t >> 6;      // wave 0..15
  const int sc = wvid >> 2, nh = (wvid >> 1) & 1, nth = wvid & 1;

  __shared__ unsigned short atile[256 * 128];  // 64 KB, XOR-swizzled bf16
  __shared__ float zb1s[H_];
  __shared__ float w2s[H_];
  __shared__ float red[16][64];
  __shared__ float mred[4], ered[4], pred[2], miscs[2];

  if (t < 512) { zb1s[t] = zb1[(size_t)b * H_ + t]; w2s[t] = W2[t]; }

  {
    const int r = t >> 2;
    const int g0 = (t & 3) * 4;
    const float* __restrict__ src = wt + ((size_t)r * B_ + b) * D_;
    #pragma unroll
    for (int gg = 0; gg < 4; ++gg) {
      const int g = g0 + gg;
      const float4 v0 = *(const float4*)(src + g * 8);
      const float4 v1 = *(const float4*)(src + g * 8 + 4);
      ushort8v u;
      u[0] = f2bf(v0.x); u[1] = f2bf(v0.y); u[2] = f2bf(v0.z); u[3] = f2bf(v0.w);
      u[4] = f2bf(v1.x); u[5] = f2bf(v1.y); u[6] = f2bf(v1.z); u[7] = f2bf(v1.w);
      *(ushort8v*)&atile[r * 128 + ((g ^ (r & 15)) << 3)] = u;
    }
  }
  __syncthreads();

  short8v afr[4][4];
  #pragma unroll
  for (int m = 0; m < 4; ++m) {
    const int arow = sc * 64 + m * 16 + (lane & 15);
    #pragma unroll
    for (int ks = 0; ks < 4; ++ks) {
      const int g = ks * 4 + (lane >> 4);
      afr[m][ks] = *(const short8v*)&atile[arow * 128 + ((g ^ (arow & 15)) << 3)];
    }
  }

  float fsum[4][4];
  #pragma unroll
  for (int m = 0; m < 4; ++m)
    #pragma unroll
    for (int j = 0; j < 4; ++j) fsum[m][j] = 0.f;

  const int hl = lane & 15;
  #pragma unroll 2
  for (int nt = 0; nt < 8; ++nt) {
    const int hblk = nh * 16 + nth * 8 + nt;
    const int hrow = hblk * 16 + hl;
    f32x4 acc0 = {0.f,0.f,0.f,0.f}, acc1 = {0.f,0.f,0.f,0.f};
    f32x4 acc2 = {0.f,0.f,0.f,0.f}, acc3 = {0.f,0.f,0.f,0.f};
    #pragma unroll
    for (int ks = 0; ks < 4; ++ks) {
      const int frag = hblk * 4 + ks;
      const short8v bfr = *(const short8v*)(Bp + ((size_t)frag << 9) + (lane << 3));
      acc0 = __builtin_amdgcn_mfma_f32_16x16x32_bf16(afr[0][ks], bfr, acc0, 0, 0, 0);
      acc1 = __builtin_amdgcn_mfma_f32_16x16x32_bf16(afr[1][ks], bfr, acc1, 0, 0, 0);
      acc2 = __builtin_amdgcn_mfma_f32_16x16x32_bf16(afr[2][ks], bfr, acc2, 0, 0, 0);
      acc3 = __builtin_amdgcn_mfma_f32_16x16x32_bf16(afr[3][ks], bfr, acc3, 0, 0, 0);
    }
    const float zv = zb1s[hrow], wgt = w2s[hrow];
    #pragma unroll
    for (int j = 0; j < 4; ++j) {
      fsum[0][j] += fmaxf(acc0[j] + zv, 0.f) * wgt;
      fsum[1][j] += fmaxf(acc1[j] + zv, 0.f) * wgt;
      fsum[2][j] += fmaxf(acc2[j] + zv, 0.f) * wgt;
      fsum[3][j] += fmaxf(acc3[j] + zv, 0.f) * wgt;
    }
  }
  #pragma unroll
  for (int m = 0; m < 4; ++m)
    #pragma unroll
    for (int j = 0; j < 4; ++j) {
      float v = fsum[m][j];
      v += __shfl_xor(v, 1); v += __shfl_xor(v, 2);
      v += __shfl_xor(v, 4); v += __shfl_xor(v, 8);
      fsum[m][j] = v;
    }
  if (hl == 0) {
    const int rb = (lane >> 4) * 4;
    #pragma unroll
    for (int m = 0; m < 4; ++m)
      #pragma unroll
      for (int j = 0; j < 4; ++j)
        red[wvid][m * 16 + rb + j] = fsum[m][j];
  }
  __syncthreads();

  float fval = 0.f;
  if (t < 256) {
    const int sc2 = t >> 6, r = t & 63;
    fval = red[sc2 * 4 + 0][r] + red[sc2 * 4 + 1][r]
         + red[sc2 * 4 + 2][r] + red[sc2 * 4 + 3][r] + b2[0];
    float mm = fval;
    #pragma unroll
    for (int o = 1; o < 64; o <<= 1) mm = fmaxf(mm, __shfl_xor(mm, o));
    if (lane == 0) mred[wvid] = mm;
  } else if (t < 384) {
    const int d = t - 256;
    float lg = bvec[d];
    #pragma unroll
    for (int kc = 0; kc < 8; ++kc) lg += l2part[((size_t)b * 8 + kc) * 128 + d];
    float term = w[b * 128 + d] * lg - softplusf(lg);
    #pragma unroll
    for (int o = 1; o < 64; o <<= 1) term += __shfl_xor(term, o);
    if (lane == 0) pred[wvid - 4] = term;
  } else if (t == 384) {
    miscs[0] = pxw_part[b * 4] + pxw_part[b * 4 + 1]
             + pxw_part[b * 4 + 2] + pxw_part[b * 4 + 3];
  } else if (t == 385) {
    miscs[1] = fzw_part[b * 8 + 0] + fzw_part[b * 8 + 1] + fzw_part[b * 8 + 2]
             + fzw_part[b * 8 + 3] + fzw_part[b * 8 + 4] + fzw_part[b * 8 + 5]
             + fzw_part[b * 8 + 6] + fzw_part[b * 8 + 7];
  }
  __syncthreads();
  if (t < 256) {
    const float mm = fmaxf(fmaxf(mred[0], mred[1]), fmaxf(mred[2], mred[3]));
    float e = expf(fval - mm);
    #pragma unroll
    for (int o = 1; o < 64; o <<= 1) e += __shfl_xor(e, o);
    if (lane == 0) ered[wvid] = e;
  }
  __syncthreads();
  if (t == 0) {
    const float mm = fmaxf(fmaxf(mred[0], mred[1]), fmaxf(mred[2], mred[3]));
    const float tot = ered[0] + ered[1] + ered[2] + ered[3];
    const float logZ = mm + logf(tot) - logf((float)S_) + (float)D_ * logf(2.f);
    const float pwx = pred[0] + pred[1];
    const float pxw = miscs[0];
    const float fzw = miscs[1] + b2[0];
    const float r_wz = fminf(fzw - logZ, 0.f);
    out[b] = -(pxw - pwx + r_wz);
  }
}

extern "C" void kernel_launch(void* const* d_in, const int* in_sizes, int n_in,
                              void* d_out, int out_size, void* d_ws, size_t ws_size,
                              hipStream_t stream) {
  const float* x    = (const float*)d_in[0];
  // d_in[1] = y, unused
  const float* w    = (const float*)d_in[2];
  const float* z    = (const float*)d_in[3];
  const float* wt   = (const float*)d_in[4];
  const float* W    = (const float*)d_in[5];
  const float* bvec = (const float*)d_in[6];
  const float* cvec = (const float*)d_in[7];
  const float* W1   = (const float*)d_in[8];
  const float* b1   = (const float*)d_in[9];
  const float* W2   = (const float*)d_in[10];
  const float* b2   = (const float*)d_in[11];

  float* ws_f = (float*)d_ws;
  float* zb1            = ws_f;                              // 65536 f
  unsigned short* Bp    = (unsigned short*)(ws_f + 65536);   // 65536 us (32768 f)
  float* l2part         = ws_f + 98304;                      // 131072 f
  float* pxw_part       = ws_f + 229376;                     // 512 f
  float* fzw_part       = ws_f + 229888;                     // 1024 f
  float* out = (float*)d_out;

  hipLaunchKernelGGL(Kprep, dim3(1856), dim3(256), 0, stream,
                     x, w, z, W, cvec, W1, b1, W2, Bp, l2part, pxw_part, zb1, fzw_part);
  // ---- attribution probe: Kmain x3 (idempotent; extra 2 replicas measure Kmain) ----
  hipLaunchKernelGGL(Kmain, dim3(B_), dim3(1024), 0, stream,
                     wt, Bp, zb1, W2, b2, l2part, bvec, w, pxw_part, fzw_part, out);
  hipLaunchKernelGGL(Kmain, dim3(B_), dim3(1024), 0, stream,
                     wt, Bp, zb1, W2, b2, l2part, bvec, w, pxw_part, fzw_part, out);
  hipLaunchKernelGGL(Kmain, dim3(B_), dim3(1024), 0, stream,
                     wt, Bp, zb1, W2, b2, l2part, bvec, w, pxw_part, fzw_part, out);
}

// Round 15
// 32.233 us; speedup vs baseline: 2.0649x; 2.0649x over previous
//
#include <hip/hip_runtime.h>
#include <hip/hip_bf16.h>
#include <math.h>

#define B_ 128
#define IN_ 1024
#define D_ 128
#define H_ 512
#define S_ 256

typedef __attribute__((ext_vector_type(8))) short short8v;
typedef __attribute__((ext_vector_type(8))) unsigned short ushort8v;
typedef __attribute__((ext_vector_type(4))) unsigned short ushort4v;
typedef __attribute__((ext_vector_type(4))) float f32x4;

__device__ __forceinline__ float softplusf(float x) {
  return fmaxf(x, 0.f) + log1pf(expf(-fabsf(x)));
}

__device__ __forceinline__ unsigned short f2bf(float f) {
  unsigned u = __float_as_uint(f);
  unsigned r = (u + 0x7fff + ((u >> 16) & 1)) >> 16;   // RNE
  return (unsigned short)r;
}

// load 8 consecutive fp32 at p, convert to bf16 fragment
__device__ __forceinline__ short8v ld_frag8(const float* __restrict__ p) {
  const float4 v0 = *(const float4*)(p);
  const float4 v1 = *(const float4*)(p + 4);
  short8v s;
  s[0] = (short)f2bf(v0.x); s[1] = (short)f2bf(v0.y);
  s[2] = (short)f2bf(v0.z); s[3] = (short)f2bf(v0.w);
  s[4] = (short)f2bf(v1.x); s[5] = (short)f2bf(v1.y);
  s[6] = (short)f2bf(v1.z); s[7] = (short)f2bf(v1.w);
  return s;
}

// ============ Kpack: fragment packs + pwx partials (1280 blocks x 256) ============
// [0,64)     : Bp  = W1 w-half fragments (verified pattern)
// [64,128)   : Bz  = W1 z-half fragments (same pattern, offset 0)
// [128,256)  : BwT = W fragments, col=i k=d (same pattern on W)
// [256,1280) : pwx partial logits (verified round-5 body)
__global__ __launch_bounds__(256) void Kpack(
    const float* __restrict__ x, const float* __restrict__ W,
    const float* __restrict__ W1,
    unsigned short* __restrict__ Bp, unsigned short* __restrict__ Bz,
    unsigned short* __restrict__ BwT, float* __restrict__ l2part) {
  __shared__ float smem[512];
  const int blk = blockIdx.x;
  const int t = threadIdx.x;

  if (blk < 128) {
    // ---- Bp / Bz: frag=hblk*4+ks, h=hblk*16+(l&15), k=ks*32+(l>>4)*8+j
    const int zhalf = (blk >= 64);
    const int o = ((blk & 63) * 256 + t) * 4;
    const int frag = o >> 9;
    const int l = (o >> 3) & 63;
    const int j0 = o & 7;
    const int h = (frag >> 2) * 16 + (l & 15);
    const int k0 = (frag & 3) * 32 + ((l >> 4) << 3) + j0;
    const float4 v = *(const float4*)(W1 + (size_t)h * 256 + (zhalf ? 0 : 128) + k0);
    ushort4v u;
    u[0] = f2bf(v.x); u[1] = f2bf(v.y); u[2] = f2bf(v.z); u[3] = f2bf(v.w);
    *(ushort4v*)((zhalf ? Bz : Bp) + o) = u;
  } else if (blk < 256) {
    // ---- BwT: frag=itile*4+ks, i=itile*16+(l&15), k(d)=ks*32+(l>>4)*8+j
    const int o = ((blk - 128) * 256 + t) * 4;
    const int frag = o >> 9;
    const int l = (o >> 3) & 63;
    const int j0 = o & 7;
    const int i = (frag >> 2) * 16 + (l & 15);
    const int k0 = (frag & 3) * 32 + ((l >> 4) << 3) + j0;
    const float4 v = *(const float4*)(W + (size_t)i * D_ + k0);
    ushort4v u;
    u[0] = f2bf(v.x); u[1] = f2bf(v.y); u[2] = f2bf(v.z); u[3] = f2bf(v.w);
    *(ushort4v*)(BwT + o) = u;
  } else {
    // ---- pwx partial (verified): (b, kc of 8), 128 i-rows
    const int bb = blk - 256;
    const int b = bb >> 3, kc = bb & 7;
    float* xs = smem;            // 128
    float* p2 = smem + 128;      // 256
    if (t < 128) xs[t] = x[b * IN_ + kc * 128 + t];
    __syncthreads();
    const int d = t & 127, ks = t >> 7;
    const float* __restrict__ Wp = W + (size_t)(kc * 128 + ks * 64) * D_ + d;
    float s = 0.f;
    #pragma unroll 8
    for (int i = 0; i < 64; ++i) s = fmaf(xs[ks * 64 + i], Wp[(size_t)i * D_], s);
    p2[ks * 128 + d] = s;
    __syncthreads();
    if (t < 128) l2part[((size_t)b * 8 + kc) * 128 + t] = p2[t] + p2[128 + t];
  }
}

// ============ Kmm: MFMA prep (96 blocks x 256) ============
// [0,64)  : pxw — logits1 = w@W^T + c, fused x*lg - softplus, reduce over i
//           block = (bt of 8, ic of 8); wave = 2 i-tiles
// [64,96) : zw — zpre = z@W1z^T, wpre = w@W1w^T; store zb1; fzw = relu(+)·W2
//           block = (bt of 8, hc of 4); wave = 2 h-tiles
__global__ __launch_bounds__(256) void Kmm(
    const float* __restrict__ w, const float* __restrict__ z,
    const float* __restrict__ x, const float* __restrict__ cvec,
    const float* __restrict__ b1, const float* __restrict__ W2,
    const unsigned short* __restrict__ Bp, const unsigned short* __restrict__ Bz,
    const unsigned short* __restrict__ BwT, float* __restrict__ zb1,
    float* __restrict__ pxw_part, float* __restrict__ fzw_part) {
  __shared__ float xs[16][128];
  __shared__ float redp[4][16];
  const int blk = blockIdx.x;
  const int t = threadIdx.x;
  const int lane = t & 63, wv = t >> 6;

  if (blk < 64) {
    // ================= pxw =================
    const int bt = blk >> 3, ic = blk & 7;
    // stage x tile [16 b][128 i]
    {
      const int row = t >> 4, c8 = (t & 15) * 8;
      const float* __restrict__ src = x + (size_t)(bt * 16 + row) * IN_ + ic * 128 + c8;
      *(float4*)&xs[row][c8]     = *(const float4*)(src);
      *(float4*)&xs[row][c8 + 4] = *(const float4*)(src + 4);
    }
    // A-fragments from w: row = bt*16 + (lane&15), k = ks*32 + (lane>>4)*8 + j
    short8v a[4];
    const int arow = bt * 16 + (lane & 15);
    const int k0 = (lane >> 4) * 8;
    #pragma unroll
    for (int ks = 0; ks < 4; ++ks)
      a[ks] = ld_frag8(w + (size_t)arow * D_ + ks * 32 + k0);
    __syncthreads();

    float term[4] = {0.f, 0.f, 0.f, 0.f};
    #pragma unroll
    for (int itl = 0; itl < 2; ++itl) {
      const int itile = wv * 2 + itl;           // 0..7
      const int git = ic * 8 + itile;           // global i-tile 0..63
      f32x4 acc = {0.f, 0.f, 0.f, 0.f};
      #pragma unroll
      for (int ks = 0; ks < 4; ++ks) {
        const short8v bfr = *(const short8v*)(BwT + ((size_t)(git * 4 + ks) << 9) + (lane << 3));
        acc = __builtin_amdgcn_mfma_f32_16x16x32_bf16(a[ks], bfr, acc, 0, 0, 0);
      }
      const int iloc = itile * 16 + (lane & 15);
      const float cv = cvec[ic * 128 + iloc];
      #pragma unroll
      for (int j = 0; j < 4; ++j) {
        const int rloc = (lane >> 4) * 4 + j;
        const float lg = acc[j] + cv;
        term[j] += xs[rloc][iloc] * lg - softplusf(lg);
      }
    }
    // reduce over the 16 i-columns (lane bits 0..3)
    #pragma unroll
    for (int j = 0; j < 4; ++j) {
      float v = term[j];
      v += __shfl_xor(v, 1); v += __shfl_xor(v, 2);
      v += __shfl_xor(v, 4); v += __shfl_xor(v, 8);
      if ((lane & 15) == 0) redp[wv][(lane >> 4) * 4 + j] = v;
    }
    __syncthreads();
    if (t < 16)
      pxw_part[(size_t)(bt * 16 + t) * 8 + ic] =
          redp[0][t] + redp[1][t] + redp[2][t] + redp[3][t];
  } else {
    // ================= zw =================
    const int bb = blk - 64;
    const int bt = bb >> 2, hc = bb & 3;
    short8v az[4], aw[4];
    const int arow = bt * 16 + (lane & 15);
    const int k0 = (lane >> 4) * 8;
    #pragma unroll
    for (int ks = 0; ks < 4; ++ks) {
      az[ks] = ld_frag8(z + (size_t)arow * D_ + ks * 32 + k0);
      aw[ks] = ld_frag8(w + (size_t)arow * D_ + ks * 32 + k0);
    }
    float term[4] = {0.f, 0.f, 0.f, 0.f};
    #pragma unroll
    for (int htl = 0; htl < 2; ++htl) {
      const int ghb = hc * 8 + wv * 2 + htl;    // global h-tile 0..31
      f32x4 accz = {0.f, 0.f, 0.f, 0.f};
      f32x4 accw = {0.f, 0.f, 0.f, 0.f};
      #pragma unroll
      for (int ks = 0; ks < 4; ++ks) {
        const size_t fo = ((size_t)(ghb * 4 + ks) << 9) + (lane << 3);
        const short8v bz = *(const short8v*)(Bz + fo);
        const short8v bw = *(const short8v*)(Bp + fo);
        accz = __builtin_amdgcn_mfma_f32_16x16x32_bf16(az[ks], bz, accz, 0, 0, 0);
        accw = __builtin_amdgcn_mfma_f32_16x16x32_bf16(aw[ks], bw, accw, 0, 0, 0);
      }
      const int h = ghb * 16 + (lane & 15);
      const float b1v = b1[h], w2v = W2[h];
      #pragma unroll
      for (int j = 0; j < 4; ++j) {
        const int brow = bt * 16 + (lane >> 4) * 4 + j;
        const float zp = accz[j] + b1v;
        zb1[(size_t)brow * H_ + h] = zp;
        term[j] += fmaxf(zp + accw[j], 0.f) * w2v;
      }
    }
    #pragma unroll
    for (int j = 0; j < 4; ++j) {
      float v = term[j];
      v += __shfl_xor(v, 1); v += __shfl_xor(v, 2);
      v += __shfl_xor(v, 4); v += __shfl_xor(v, 8);
      if ((lane & 15) == 0) redp[wv][(lane >> 4) * 4 + j] = v;
    }
    __syncthreads();
    if (t < 16)
      fzw_part[(size_t)(bt * 16 + t) * 4 + hc] =
          redp[0][t] + redp[1][t] + redp[2][t] + redp[3][t];
  }
}

// ============ main fused kernel: one block per b (finisher partials updated) ============
__global__ __launch_bounds__(1024) void Kmain(
    const float* __restrict__ wt, const unsigned short* __restrict__ Bp,
    const float* __restrict__ zb1, const float* __restrict__ W2,
    const float* __restrict__ b2, const float* __restrict__ l2part,
    const float* __restrict__ bvec, const float* __restrict__ w,
    const float* __restrict__ pxw_part, const float* __restrict__ fzw_part,
    float* __restrict__ out) {
  const int b = blockIdx.x;
  const int t = threadIdx.x;
  const int lane = t & 63, wvid = t >> 6;      // wave 0..15
  const int sc = wvid >> 2, nh = (wvid >> 1) & 1, nth = wvid & 1;

  __shared__ unsigned short atile[256 * 128];  // 64 KB, XOR-swizzled bf16
  __shared__ float zb1s[H_];
  __shared__ float w2s[H_];
  __shared__ float red[16][64];
  __shared__ float mred[4], ered[4], pred[2], miscs[2];

  if (t < 512) { zb1s[t] = zb1[(size_t)b * H_ + t]; w2s[t] = W2[t]; }

  {
    const int r = t >> 2;
    const int g0 = (t & 3) * 4;
    const float* __restrict__ src = wt + ((size_t)r * B_ + b) * D_;
    #pragma unroll
    for (int gg = 0; gg < 4; ++gg) {
      const int g = g0 + gg;
      const float4 v0 = *(const float4*)(src + g * 8);
      const float4 v1 = *(const float4*)(src + g * 8 + 4);
      ushort8v u;
      u[0] = f2bf(v0.x); u[1] = f2bf(v0.y); u[2] = f2bf(v0.z); u[3] = f2bf(v0.w);
      u[4] = f2bf(v1.x); u[5] = f2bf(v1.y); u[6] = f2bf(v1.z); u[7] = f2bf(v1.w);
      *(ushort8v*)&atile[r * 128 + ((g ^ (r & 15)) << 3)] = u;
    }
  }
  __syncthreads();

  short8v afr[4][4];
  #pragma unroll
  for (int m = 0; m < 4; ++m) {
    const int arow = sc * 64 + m * 16 + (lane & 15);
    #pragma unroll
    for (int ks = 0; ks < 4; ++ks) {
      const int g = ks * 4 + (lane >> 4);
      afr[m][ks] = *(const short8v*)&atile[arow * 128 + ((g ^ (arow & 15)) << 3)];
    }
  }

  float fsum[4][4];
  #pragma unroll
  for (int m = 0; m < 4; ++m)
    #pragma unroll
    for (int j = 0; j < 4; ++j) fsum[m][j] = 0.f;

  const int hl = lane & 15;
  #pragma unroll 2
  for (int nt = 0; nt < 8; ++nt) {
    const int hblk = nh * 16 + nth * 8 + nt;
    const int hrow = hblk * 16 + hl;
    f32x4 acc0 = {0.f,0.f,0.f,0.f}, acc1 = {0.f,0.f,0.f,0.f};
    f32x4 acc2 = {0.f,0.f,0.f,0.f}, acc3 = {0.f,0.f,0.f,0.f};
    #pragma unroll
    for (int ks = 0; ks < 4; ++ks) {
      const int frag = hblk * 4 + ks;
      const short8v bfr = *(const short8v*)(Bp + ((size_t)frag << 9) + (lane << 3));
      acc0 = __builtin_amdgcn_mfma_f32_16x16x32_bf16(afr[0][ks], bfr, acc0, 0, 0, 0);
      acc1 = __builtin_amdgcn_mfma_f32_16x16x32_bf16(afr[1][ks], bfr, acc1, 0, 0, 0);
      acc2 = __builtin_amdgcn_mfma_f32_16x16x32_bf16(afr[2][ks], bfr, acc2, 0, 0, 0);
      acc3 = __builtin_amdgcn_mfma_f32_16x16x32_bf16(afr[3][ks], bfr, acc3, 0, 0, 0);
    }
    const float zv = zb1s[hrow], wgt = w2s[hrow];
    #pragma unroll
    for (int j = 0; j < 4; ++j) {
      fsum[0][j] += fmaxf(acc0[j] + zv, 0.f) * wgt;
      fsum[1][j] += fmaxf(acc1[j] + zv, 0.f) * wgt;
      fsum[2][j] += fmaxf(acc2[j] + zv, 0.f) * wgt;
      fsum[3][j] += fmaxf(acc3[j] + zv, 0.f) * wgt;
    }
  }
  #pragma unroll
  for (int m = 0; m < 4; ++m)
    #pragma unroll
    for (int j = 0; j < 4; ++j) {
      float v = fsum[m][j];
      v += __shfl_xor(v, 1); v += __shfl_xor(v, 2);
      v += __shfl_xor(v, 4); v += __shfl_xor(v, 8);
      fsum[m][j] = v;
    }
  if (hl == 0) {
    const int rb = (lane >> 4) * 4;
    #pragma unroll
    for (int m = 0; m < 4; ++m)
      #pragma unroll
      for (int j = 0; j < 4; ++j)
        red[wvid][m * 16 + rb + j] = fsum[m][j];
  }
  __syncthreads();

  float fval = 0.f;
  if (t < 256) {
    const int sc2 = t >> 6, r = t & 63;
    fval = red[sc2 * 4 + 0][r] + red[sc2 * 4 + 1][r]
         + red[sc2 * 4 + 2][r] + red[sc2 * 4 + 3][r] + b2[0];
    float mm = fval;
    #pragma unroll
    for (int o = 1; o < 64; o <<= 1) mm = fmaxf(mm, __shfl_xor(mm, o));
    if (lane == 0) mred[wvid] = mm;
  } else if (t < 384) {
    const int d = t - 256;
    float lg = bvec[d];
    #pragma unroll
    for (int kc = 0; kc < 8; ++kc) lg += l2part[((size_t)b * 8 + kc) * 128 + d];
    float term = w[b * 128 + d] * lg - softplusf(lg);
    #pragma unroll
    for (int o = 1; o < 64; o <<= 1) term += __shfl_xor(term, o);
    if (lane == 0) pred[wvid - 4] = term;
  } else if (t == 384) {
    float s = 0.f;
    #pragma unroll
    for (int ic = 0; ic < 8; ++ic) s += pxw_part[(size_t)b * 8 + ic];
    miscs[0] = s;
  } else if (t == 385) {
    float s = 0.f;
    #pragma unroll
    for (int hc = 0; hc < 4; ++hc) s += fzw_part[(size_t)b * 4 + hc];
    miscs[1] = s;
  }
  __syncthreads();
  if (t < 256) {
    const float mm = fmaxf(fmaxf(mred[0], mred[1]), fmaxf(mred[2], mred[3]));
    float e = expf(fval - mm);
    #pragma unroll
    for (int o = 1; o < 64; o <<= 1) e += __shfl_xor(e, o);
    if (lane == 0) ered[wvid] = e;
  }
  __syncthreads();
  if (t == 0) {
    const float mm = fmaxf(fmaxf(mred[0], mred[1]), fmaxf(mred[2], mred[3]));
    const float tot = ered[0] + ered[1] + ered[2] + ered[3];
    const float logZ = mm + logf(tot) - logf((float)S_) + (float)D_ * logf(2.f);
    const float pwx = pred[0] + pred[1];
    const float pxw = miscs[0];
    const float fzw = miscs[1] + b2[0];
    const float r_wz = fminf(fzw - logZ, 0.f);
    out[b] = -(pxw - pwx + r_wz);
  }
}

extern "C" void kernel_launch(void* const* d_in, const int* in_sizes, int n_in,
                              void* d_out, int out_size, void* d_ws, size_t ws_size,
                              hipStream_t stream) {
  const float* x    = (const float*)d_in[0];
  // d_in[1] = y, unused
  const float* w    = (const float*)d_in[2];
  const float* z    = (const float*)d_in[3];
  const float* wt   = (const float*)d_in[4];
  const float* W    = (const float*)d_in[5];
  const float* bvec = (const float*)d_in[6];
  const float* cvec = (const float*)d_in[7];
  const float* W1   = (const float*)d_in[8];
  const float* b1   = (const float*)d_in[9];
  const float* W2   = (const float*)d_in[10];
  const float* b2   = (const float*)d_in[11];

  float* ws_f = (float*)d_ws;
  unsigned short* Bp    = (unsigned short*)ws_f;              // 65536 us = 32768 f
  unsigned short* Bz    = (unsigned short*)(ws_f + 32768);    // 65536 us
  unsigned short* BwT   = (unsigned short*)(ws_f + 65536);    // 131072 us = 65536 f
  float* zb1            = ws_f + 131072;                      // 65536 f
  float* l2part         = ws_f + 196608;                      // 131072 f
  float* pxw_part       = ws_f + 327680;                      // 1024 f
  float* fzw_part       = ws_f + 328704;                      // 512 f
  float* out = (float*)d_out;

  hipLaunchKernelGGL(Kpack, dim3(1280), dim3(256), 0, stream,
                     x, W, W1, Bp, Bz, BwT, l2part);
  hipLaunchKernelGGL(Kmm, dim3(96), dim3(256), 0, stream,
                     w, z, x, cvec, b1, W2, Bp, Bz, BwT, zb1, pxw_part, fzw_part);
  hipLaunchKernelGGL(Kmain, dim3(B_), dim3(1024), 0, stream,
                     wt, Bp, zb1, W2, b2, l2part, bvec, w, pxw_part, fzw_part, out);
}